// Round 4
// baseline (305.831 us; speedup 1.0000x reference)
//
#include <hip/hip_runtime.h>
#include <cstdint>
#include <cstddef>

#define NB 64
#define NN 2048
#define ND 128
#define NK 1024
#define NTOT (NB * NN)        // 131072
#define EPG4 (NN * 32 / 4)    // 16384 int4 per graph
#define P 8                   // slices per graph
#define SLICE4 (EPG4 / P)     // 2048 int4 per slice
#define PROJ_BLOCKS (NTOT / 4)  // 32768 blocks, one wave per node

typedef float vf4 __attribute__((ext_vector_type(4)));
typedef unsigned long long ull;

// ---------------- fused: project (blocks [0,32768)) + degree hist (next 512) ----------------
__global__ __launch_bounds__(256) void k_ph(const float* __restrict__ feat,
                                            const float* __restrict__ W,
                                            float* __restrict__ s,
                                            const int4* __restrict__ src4,
                                            const int4* __restrict__ dst4,
                                            unsigned* __restrict__ part_o,
                                            unsigned* __restrict__ part_i) {
    __shared__ unsigned ho[NN];
    __shared__ unsigned hi2[NN];
    int blk = blockIdx.x;
    if (blk < PROJ_BLOCKS) {
        int node = blk * 4 + (threadIdx.x >> 6);
        int lane = threadIdx.x & 63;
        float2 v  = ((const float2*)(feat + (size_t)node * ND))[lane];
        float2 w2 = ((const float2*)W)[lane];
        float val = fmaf(v.x, w2.x, v.y * w2.y);
        #pragma unroll
        for (int off = 32; off > 0; off >>= 1) val += __shfl_down(val, off);
        if (lane == 0) s[node] = val;
    } else {
        int hb = blk - PROJ_BLOCKS;   // 0..511
        int tid = threadIdx.x;
        for (int j = tid; j < NN; j += 256) { ho[j] = 0u; hi2[j] = 0u; }
        __syncthreads();
        const int4* sp = src4 + (size_t)hb * SLICE4;
        const int4* dp = dst4 + (size_t)hb * SLICE4;
        for (int i = tid; i < SLICE4; i += 256) {
            int4 a = sp[i];
            int4 b = dp[i];
            atomicAdd(&ho[a.x & (NN - 1)], 1u); atomicAdd(&ho[a.y & (NN - 1)], 1u);
            atomicAdd(&ho[a.z & (NN - 1)], 1u); atomicAdd(&ho[a.w & (NN - 1)], 1u);
            atomicAdd(&hi2[b.x & (NN - 1)], 1u); atomicAdd(&hi2[b.y & (NN - 1)], 1u);
            atomicAdd(&hi2[b.z & (NN - 1)], 1u); atomicAdd(&hi2[b.w & (NN - 1)], 1u);
        }
        __syncthreads();
        unsigned* po = part_o + (size_t)hb * NN;
        unsigned* pi = part_i + (size_t)hb * NN;
        for (int j = tid; j < NN; j += 256) { po[j] = ho[j]; pi[j] = hi2[j]; }
    }
}

// ---------------- reduce degree partials -> m, inv_in ----------------
__global__ void k_msg(const unsigned* __restrict__ part_o, const unsigned* __restrict__ part_i,
                      const float* __restrict__ s, float* __restrict__ m,
                      float* __restrict__ inv_in) {
    int node = blockIdx.x * blockDim.x + threadIdx.x;
    int g = node >> 11, local = node & (NN - 1);
    const unsigned* po = part_o + (size_t)g * P * NN + local;
    const unsigned* pi = part_i + (size_t)g * P * NN + local;
    unsigned od = 0, id2 = 0;
    #pragma unroll
    for (int p = 0; p < P; p++) { od += po[(size_t)p * NN]; id2 += pi[(size_t)p * NN]; }
    m[node] = s[node] * rsqrtf(fmaxf((float)od, 1.0f));
    inv_in[node] = rsqrtf(fmaxf((float)id2, 1.0f));
}

// ---------------- per-slice scatter (LDS), partials to global ----------------
__global__ __launch_bounds__(256) void k_scatter(const int4* __restrict__ src4,
                                                 const int4* __restrict__ dst4,
                                                 const float* __restrict__ m,
                                                 float* __restrict__ part_a) {
    __shared__ float ms[NN];
    __shared__ float acc[NN];
    int blk = blockIdx.x, tid = threadIdx.x;
    int g = blk >> 3;
    for (int j = tid; j < NN; j += 256) { ms[j] = m[g * NN + j]; acc[j] = 0.0f; }
    __syncthreads();
    const int4* sp = src4 + (size_t)blk * SLICE4;
    const int4* dp = dst4 + (size_t)blk * SLICE4;
    for (int i = tid; i < SLICE4; i += 256) {
        int4 a = sp[i];
        int4 b = dp[i];
        atomicAdd(&acc[b.x & (NN - 1)], ms[a.x & (NN - 1)]);
        atomicAdd(&acc[b.y & (NN - 1)], ms[a.y & (NN - 1)]);
        atomicAdd(&acc[b.z & (NN - 1)], ms[a.z & (NN - 1)]);
        atomicAdd(&acc[b.w & (NN - 1)], ms[a.w & (NN - 1)]);
    }
    __syncthreads();
    float* pa = part_a + (size_t)blk * NN;
    for (int j = tid; j < NN; j += 256) pa[j] = acc[j];
}

// ---------------- reduce scatter partials -> score, tanh, key, expsum ----------------
__global__ __launch_bounds__(256) void k_score(const float* __restrict__ part_a,
                                               const float* __restrict__ inv_in,
                                               const float* __restrict__ bptr,
                                               float* __restrict__ score_g,
                                               float* __restrict__ t_g,
                                               ull* __restrict__ keys,
                                               float* __restrict__ expsum) {
    __shared__ float wsum[4];
    int node = blockIdx.x * blockDim.x + threadIdx.x;
    int g = node >> 11, local = node & (NN - 1);
    const float* pa = part_a + (size_t)g * P * NN + local;
    float a = 0.0f;
    #pragma unroll
    for (int p = 0; p < P; p++) a += pa[(size_t)p * NN];   // fixed order: deterministic
    float sc = a * inv_in[node] + bptr[0];
    score_g[node] = sc;
    t_g[node] = tanhf(sc);
    unsigned u  = __float_as_uint(sc);
    unsigned ok = (u & 0x80000000u) ? ~u : (u | 0x80000000u);   // order-preserving
    keys[node] = ((ull)(~ok) << 32) | (unsigned)local;          // asc key == desc score, asc idx
    float e = expf(sc);
    #pragma unroll
    for (int off = 32; off > 0; off >>= 1) e += __shfl_down(e, off);
    int lane = threadIdx.x & 63, w = threadIdx.x >> 6;
    if (lane == 0) wsum[w] = e;
    __syncthreads();
    if (threadIdx.x == 0) atomicAdd(expsum, wsum[0] + wsum[1] + wsum[2] + wsum[3]);
}

// ---------------- rank by counting: rank(i) = #{j : key(j) < key(i)} ----------------
__global__ __launch_bounds__(256) void k_rank(const ull* __restrict__ keys,
                                              int* __restrict__ rank) {
    __shared__ ull lk[NN];
    int blk = blockIdx.x;             // NB*8 blocks
    int g = blk >> 3, chunk = blk & 7;
    int tid = threadIdx.x;
    for (int j = tid; j < NN; j += 256) lk[j] = keys[(size_t)g * NN + j];
    __syncthreads();
    ull mk = lk[chunk * 256 + tid];
    int r = 0;
    #pragma unroll 8
    for (int j = 0; j < NN; j++) r += (lk[j] < mk) ? 1 : 0;   // LDS broadcast, conflict-free
    rank[g * NN + chunk * 256 + tid] = r;
}

// ---------------- scan: perm (rank order), complement (index order), drow ----------------
__global__ __launch_bounds__(1024) void k_scan(const int* __restrict__ rank,
                                               int* __restrict__ drow,
                                               float* __restrict__ perm_f,
                                               float* __restrict__ permc_f) {
    __shared__ int lperm[NK];
    __shared__ int lcomp[NK];
    __shared__ int wtot[16];
    __shared__ int wbase[16];
    int g = blockIdx.x, tid = threadIdx.x;
    int2 rr = ((const int2*)(rank + (size_t)g * NN))[tid];   // elems 2t, 2t+1
    int gi0 = g * NN + 2 * tid, gi1 = gi0 + 1;
    bool u0 = rr.x >= NK, u1 = rr.y >= NK;                   // unselected flags
    ull b0 = __ballot(u0), b1 = __ballot(u1);
    int lane = tid & 63, w = tid >> 6;
    ull below = (lane == 0) ? 0ull : (~0ull >> (64 - lane));
    int p0 = __popcll(b0 & below) + __popcll(b1 & below);
    int p1 = p0 + (u0 ? 1 : 0);
    if (lane == 0) wtot[w] = __popcll(b0) + __popcll(b1);
    __syncthreads();
    if (tid == 0) {
        int s2 = 0;
        #pragma unroll
        for (int i = 0; i < 16; i++) { wbase[i] = s2; s2 += wtot[i]; }
    }
    __syncthreads();
    int base = wbase[w];
    if (u0) { int pos = base + p0; lcomp[pos] = gi0; drow[gi0] = NB * NK + g * NK + pos; }
    else    { lperm[rr.x] = gi0;   drow[gi0] = g * NK + rr.x; }
    if (u1) { int pos = base + p1; lcomp[pos] = gi1; drow[gi1] = NB * NK + g * NK + pos; }
    else    { lperm[rr.y] = gi1;   drow[gi1] = g * NK + rr.y; }
    __syncthreads();
    perm_f[g * NK + tid]  = (float)lperm[tid];
    permc_f[g * NK + tid] = (float)lcomp[tid];
}

// ---------------- emit: feat pass -> out_full + out_dist|out_com + softmax ----------------
__global__ void k_emit(const vf4* __restrict__ feat4, const float* __restrict__ t,
                       const float* __restrict__ score, const float* __restrict__ expsum,
                       const int* __restrict__ drow, vf4* __restrict__ out_full,
                       vf4* __restrict__ out_distcom, float* __restrict__ out_sm) {
    int i = blockIdx.x * blockDim.x + threadIdx.x;  // NTOT*32 threads
    int row = i >> 5, col = i & 31;
    float tv = t[row];
    vf4 v = feat4[i];
    vf4 r = v * tv;
    __builtin_nontemporal_store(r, &out_full[i]);
    __builtin_nontemporal_store(r, &out_distcom[(size_t)drow[row] * 32 + col]);
    if (col == 0) out_sm[row] = expf(score[row]) * (1.0f / expsum[0]);
}

extern "C" void kernel_launch(void* const* d_in, const int* in_sizes, int n_in,
                              void* d_out, int out_size, void* d_ws, size_t ws_size,
                              hipStream_t stream) {
    const float* feat = (const float*)d_in[0];
    const float* W    = (const float*)d_in[1];
    const float* b    = (const float*)d_in[2];
    const int*   src  = (const int*)d_in[3];
    const int*   dst  = (const int*)d_in[4];
    float* out = (float*)d_out;

    // workspace layout (8B-aligned: keys first after expsum pad)
    float* expsum = (float*)d_ws;                    // 64
    ull*   keys   = (ull*)(expsum + 64);             // NTOT
    float* s      = (float*)(keys + NTOT);           // NTOT
    float* score  = s + NTOT;                        // NTOT
    float* t      = score + NTOT;                    // NTOT
    float* m      = t + NTOT;                        // NTOT
    float* inv_in = m + NTOT;                        // NTOT
    int*   drow   = (int*)(inv_in + NTOT);           // NTOT
    int*   rank   = drow + NTOT;                     // NTOT
    unsigned* part_o = (unsigned*)(rank + NTOT);     // NB*P*NN
    unsigned* part_i = part_o + (size_t)NB * P * NN; // NB*P*NN
    float* part_a    = (float*)(part_i + (size_t)NB * P * NN); // NB*P*NN

    // output layout (floats)
    float* out_dist  = out;                           // dist|com contiguous
    float* out_full  = out + 2 * (size_t)NB * NK * ND;
    float* out_perm  = out_full + (size_t)NTOT * ND;
    float* out_permc = out_perm + NB * NK;
    float* out_sm    = out_permc + NB * NK;

    hipMemsetAsync(expsum, 0, 64 * sizeof(float), stream);

    k_ph<<<PROJ_BLOCKS + NB * P, 256, 0, stream>>>(feat, W, s, (const int4*)src,
                                                   (const int4*)dst, part_o, part_i);
    k_msg<<<NTOT / 256, 256, 0, stream>>>(part_o, part_i, s, m, inv_in);
    k_scatter<<<NB * P, 256, 0, stream>>>((const int4*)src, (const int4*)dst, m, part_a);
    k_score<<<NTOT / 256, 256, 0, stream>>>(part_a, inv_in, b, score, t, keys, expsum);
    k_rank<<<NB * P, 256, 0, stream>>>(keys, rank);
    k_scan<<<NB, 1024, 0, stream>>>(rank, drow, out_perm, out_permc);
    k_emit<<<NTOT * 32 / 256, 256, 0, stream>>>((const vf4*)feat, t, score, expsum, drow,
                                                (vf4*)out_full, (vf4*)out_dist, out_sm);
}